// Round 1
// baseline (509.282 us; speedup 1.0000x reference)
//
#include <hip/hip_runtime.h>
#include <hip/hip_bf16.h>

// HCNet: L=4 hyper-connection blocks, N=4, D=2048, B*T=4096 tokens.
// Strategy: bf16 state in ws, bf16 MFMA for the per-block DxD GEMM.
// Kernels: transpose_wblk (once) + per block {width, gemm, depth}.

#define DD 2048
#define NN 4
#define LL 4
#define NTOK 4096
#define EPSF 1e-5f

typedef __attribute__((ext_vector_type(8))) short bf16x8;
typedef __attribute__((ext_vector_type(4))) float f32x4;

__device__ __forceinline__ float bf2f(short u) {
  union { unsigned int i; float f; } v;
  v.i = ((unsigned int)(unsigned short)u) << 16;
  return v.f;
}
__device__ __forceinline__ short f2bf(float f) {
  union { float f; unsigned int i; } v; v.f = f;
  unsigned int x = v.i;
  return (short)((x + 0x7fffu + ((x >> 16) & 1u)) >> 16);  // RNE
}
__device__ __forceinline__ float wred(float v) {
#pragma unroll
  for (int off = 32; off > 0; off >>= 1) v += __shfl_xor(v, off, 64);
  return v;
}
__device__ __forceinline__ void ld16(const void* g, void* l) {
  __builtin_amdgcn_global_load_lds(
      (const __attribute__((address_space(1))) void*)g,
      (__attribute__((address_space(3))) void*)l, 16, 0, 0);
}

// ---------------- transpose Wblk[l][d][e] (f32) -> Wt[l][e][d] (bf16) -------
__global__ __launch_bounds__(256) void transpose_wblk(
    const float* __restrict__ W, short* __restrict__ Wt) {
  __shared__ float tile[64][65];
  const int blk = blockIdx.z;
  const int c0 = blockIdx.x * 64;  // source col (= dest row) base
  const int r0 = blockIdx.y * 64;  // source row (= dest col) base
  const float* Ws = W + (size_t)blk * DD * DD;
  short* Wd = Wt + (size_t)blk * DD * DD;
  const int tx = threadIdx.x & 63, ty = threadIdx.x >> 6;
#pragma unroll
  for (int r = 0; r < 16; r++) {
    const int row = ty + r * 4;
    tile[row][tx] = Ws[(size_t)(r0 + row) * DD + c0 + tx];
  }
  __syncthreads();
#pragma unroll
  for (int r = 0; r < 16; r++) {
    const int row = ty + r * 4;
    Wd[(size_t)(c0 + row) * DD + r0 + tx] = f2bf(tile[tx][row]);
  }
}

// ---------------- width connections (+ pre-norm of h) -----------------------
// one wave per token; lane owns d = lane*8 + j*512 + {0..7}, j=0..3
template <bool FIRST>
__global__ __launch_bounds__(256) void width_kernel(
    const float* __restrict__ x, short* __restrict__ Hst,
    short* __restrict__ hnorm, const float* __restrict__ A_m,
    const float* __restrict__ A_r, const float* __restrict__ W_m,
    const float* __restrict__ W_r, const float* __restrict__ s_a,
    const float* __restrict__ dyn_gamma, const float* __restrict__ norm_gamma,
    const float* __restrict__ norm_beta, int blk) {
  const int wave = threadIdx.x >> 6;
  const int lane = threadIdx.x & 63;
  const int tok = blockIdx.x * 4 + wave;
  const float* dg = dyn_gamma + blk * DD;
  const float* wm = W_m + blk * DD;
  const float* wr = W_r + (size_t)blk * DD * NN;

  bf16x8 hreg[NN][4];
  if (FIRST) {
    const float* xr = x + (size_t)tok * DD;
#pragma unroll
    for (int j = 0; j < 4; j++) {
      const int d0 = lane * 8 + j * 512;
      f32x4 a = *(const f32x4*)(xr + d0);
      f32x4 b = *(const f32x4*)(xr + d0 + 4);
      bf16x8 p;
#pragma unroll
      for (int q = 0; q < 4; q++) { p[q] = f2bf(a[q]); p[4 + q] = f2bf(b[q]); }
#pragma unroll
      for (int n = 0; n < NN; n++) hreg[n][j] = p;
    }
  } else {
    const short* Hr = Hst + (size_t)tok * NN * DD;
#pragma unroll
    for (int n = 0; n < NN; n++)
#pragma unroll
      for (int j = 0; j < 4; j++) {
        const int d0 = lane * 8 + j * 512;
        hreg[n][j] = *(const bf16x8*)(Hr + n * DD + d0);
      }
  }

  float sH[NN] = {0, 0, 0, 0}, sH2[NN] = {0, 0, 0, 0};
  float S1[NN][5];
  float S0[5] = {0, 0, 0, 0, 0};
#pragma unroll
  for (int n = 0; n < NN; n++)
#pragma unroll
    for (int m = 0; m < 5; m++) S1[n][m] = 0.f;

#pragma unroll
  for (int j = 0; j < 4; j++) {
    const int d0 = lane * 8 + j * 512;
    f32x4 g0 = *(const f32x4*)(dg + d0), g1 = *(const f32x4*)(dg + d0 + 4);
    f32x4 m0 = *(const f32x4*)(wm + d0), m1 = *(const f32x4*)(wm + d0 + 4);
    f32x4 rr[8];
#pragma unroll
    for (int q = 0; q < 8; q++) rr[q] = *(const f32x4*)(wr + (size_t)(d0 + q) * NN);
#pragma unroll
    for (int q = 0; q < 8; q++) {
      const float g = (q < 4) ? g0[q] : g1[q - 4];
      const float wmv = (q < 4) ? m0[q] : m1[q - 4];
      float gw[5];
      gw[0] = g * wmv;
      gw[1] = g * rr[q][0]; gw[2] = g * rr[q][1];
      gw[3] = g * rr[q][2]; gw[4] = g * rr[q][3];
#pragma unroll
      for (int m = 0; m < 5; m++) S0[m] += gw[m];
#pragma unroll
      for (int n = 0; n < NN; n++) {
        const float hv = bf2f(hreg[n][j][q]);
        sH[n] += hv; sH2[n] += hv * hv;
#pragma unroll
        for (int m = 0; m < 5; m++) S1[n][m] += hv * gw[m];
      }
    }
  }
#pragma unroll
  for (int n = 0; n < NN; n++) { sH[n] = wred(sH[n]); sH2[n] = wred(sH2[n]); }
#pragma unroll
  for (int m = 0; m < 5; m++) S0[m] = wred(S0[m]);
#pragma unroll
  for (int n = 0; n < NN; n++)
#pragma unroll
    for (int m = 0; m < 5; m++) S1[n][m] = wred(S1[n][m]);

  const float sa = s_a[blk];
  float Am[NN], Ar[NN][NN];
#pragma unroll
  for (int n = 0; n < NN; n++) {
    const float mu = sH[n] * (1.f / DD);
    const float var = sH2[n] * (1.f / DD) - mu * mu;
    const float inv = rsqrtf(var + EPSF);
    Am[n] = A_m[blk * NN + n] + sa * tanhf(inv * (S1[n][0] - mu * S0[0]));
#pragma unroll
    for (int m = 0; m < NN; m++)
      Ar[n][m] = A_r[blk * NN * NN + n * NN + m] +
                 sa * tanhf(inv * (S1[n][1 + m] - mu * S0[1 + m]));
  }

  short* Ho = Hst + (size_t)tok * NN * DD;
  float hbuf[4][8];
  float sh = 0.f, sh2 = 0.f;
#pragma unroll
  for (int j = 0; j < 4; j++) {
    const int d0 = lane * 8 + j * 512;
    bf16x8 outp[NN];
#pragma unroll
    for (int q = 0; q < 8; q++) {
      float a0 = 0.f, am0 = 0.f, am1 = 0.f, am2 = 0.f, am3 = 0.f;
#pragma unroll
      for (int n = 0; n < NN; n++) {
        const float hv = bf2f(hreg[n][j][q]);
        a0 += hv * Am[n];
        am0 += hv * Ar[n][0];
        am1 += hv * Ar[n][1];
        am2 += hv * Ar[n][2];
        am3 += hv * Ar[n][3];
      }
      hbuf[j][q] = a0; sh += a0; sh2 += a0 * a0;
      outp[0][q] = f2bf(am0); outp[1][q] = f2bf(am1);
      outp[2][q] = f2bf(am2); outp[3][q] = f2bf(am3);
    }
#pragma unroll
    for (int m = 0; m < NN; m++) *(bf16x8*)(Ho + m * DD + d0) = outp[m];
  }
  sh = wred(sh); sh2 = wred(sh2);
  const float mu = sh * (1.f / DD);
  const float inv = rsqrtf(sh2 * (1.f / DD) - mu * mu + EPSF);
  const float* ng = norm_gamma + blk * DD;
  const float* nb = norm_beta + blk * DD;
  short* hn = hnorm + (size_t)tok * DD;
#pragma unroll
  for (int j = 0; j < 4; j++) {
    const int d0 = lane * 8 + j * 512;
    f32x4 g0 = *(const f32x4*)(ng + d0), g1 = *(const f32x4*)(ng + d0 + 4);
    f32x4 b0 = *(const f32x4*)(nb + d0), b1 = *(const f32x4*)(nb + d0 + 4);
    bf16x8 o;
#pragma unroll
    for (int q = 0; q < 8; q++) {
      const float g = (q < 4) ? g0[q] : g1[q - 4];
      const float b = (q < 4) ? b0[q] : b1[q - 4];
      o[q] = f2bf((hbuf[j][q] - mu) * inv * g + b);
    }
    *(bf16x8*)(hn + d0) = o;
  }
}

// ---------------- block GEMM: h2 = hnorm @ Wblk + bblk ----------------------
// C[M=4096][2048] = A[M][K=2048] * Bt[N=2048][K]^T, all bf16, m97 structure.
__global__ __launch_bounds__(256) void gemm_kernel(
    const short* __restrict__ A, const short* __restrict__ Bt,
    const float* __restrict__ bias, short* __restrict__ C) {
  __shared__ short lA[128 * 64];
  __shared__ short lB[128 * 64];
  const int tid = threadIdx.x;
  const int lane = tid & 63;
  const int wave = tid >> 6;
  const int m0 = blockIdx.x * 128, n0 = blockIdx.y * 128;
  const int wm = wave >> 1, wn = wave & 1;

  f32x4 acc[4][4] = {};

  for (int kt = 0; kt < 32; ++kt) {
    const int k0 = kt * 64;
#pragma unroll
    for (int c = 0; c < 4; c++) {
      const int idx = c * 256 + tid;
      const int row = idx >> 3;
      const int col = (idx & 7) * 8;
      ld16(A + (size_t)(m0 + row) * DD + k0 + col, (char*)lA + idx * 16);
      ld16(Bt + (size_t)(n0 + row) * DD + k0 + col, (char*)lB + idx * 16);
    }
    __syncthreads();
#pragma unroll
    for (int kk = 0; kk < 2; ++kk) {
      bf16x8 af[4], bfr[4];
#pragma unroll
      for (int m = 0; m < 4; m++)
        af[m] = *(const bf16x8*)(lA + (wm * 64 + m * 16 + (lane & 15)) * 64 +
                                 kk * 32 + (lane >> 4) * 8);
#pragma unroll
      for (int n = 0; n < 4; n++)
        bfr[n] = *(const bf16x8*)(lB + (wn * 64 + n * 16 + (lane & 15)) * 64 +
                                  kk * 32 + (lane >> 4) * 8);
#pragma unroll
      for (int m = 0; m < 4; m++)
#pragma unroll
        for (int n = 0; n < 4; n++)
          acc[m][n] = __builtin_amdgcn_mfma_f32_16x16x32_bf16(
              af[m], bfr[n], acc[m][n], 0, 0, 0);
    }
    __syncthreads();
  }
#pragma unroll
  for (int n = 0; n < 4; n++) {
    const int col = n0 + wn * 64 + n * 16 + (lane & 15);
    const float bv = bias[col];
#pragma unroll
    for (int m = 0; m < 4; m++) {
      const int rbase = m0 + wm * 64 + m * 16 + ((lane >> 4) << 2);
#pragma unroll
      for (int j = 0; j < 4; j++)
        C[(size_t)(rbase + j) * DD + col] = f2bf(acc[m][n][j] + bv);
    }
  }
}

// ---------------- depth connections -----------------------------------------
template <bool LAST>
__global__ __launch_bounds__(256) void depth_kernel(
    const short* __restrict__ h2, short* __restrict__ Hst,
    float* __restrict__ out, const float* __restrict__ Bp,
    const float* __restrict__ W_b, const float* __restrict__ s_b,
    const float* __restrict__ dyn_gamma, int blk) {
  const int wave = threadIdx.x >> 6;
  const int lane = threadIdx.x & 63;
  const int tok = blockIdx.x * 4 + wave;
  const short* hr = h2 + (size_t)tok * DD;
  const float* dg = dyn_gamma + blk * DD;
  const float* wb = W_b + (size_t)blk * DD * NN;

  bf16x8 h2r[4];
  float s1 = 0.f, s2 = 0.f, T1[NN] = {0, 0, 0, 0}, T0[NN] = {0, 0, 0, 0};
#pragma unroll
  for (int j = 0; j < 4; j++) {
    const int d0 = lane * 8 + j * 512;
    h2r[j] = *(const bf16x8*)(hr + d0);
    f32x4 g0 = *(const f32x4*)(dg + d0), g1 = *(const f32x4*)(dg + d0 + 4);
    f32x4 rr[8];
#pragma unroll
    for (int q = 0; q < 8; q++) rr[q] = *(const f32x4*)(wb + (size_t)(d0 + q) * NN);
#pragma unroll
    for (int q = 0; q < 8; q++) {
      const float g = (q < 4) ? g0[q] : g1[q - 4];
      const float hv = bf2f(h2r[j][q]);
      s1 += hv; s2 += hv * hv;
#pragma unroll
      for (int n = 0; n < NN; n++) {
        const float gw = g * rr[q][n];
        T0[n] += gw; T1[n] += hv * gw;
      }
    }
  }
  s1 = wred(s1); s2 = wred(s2);
#pragma unroll
  for (int n = 0; n < NN; n++) { T0[n] = wred(T0[n]); T1[n] = wred(T1[n]); }
  const float mu = s1 * (1.f / DD);
  const float inv = rsqrtf(s2 * (1.f / DD) - mu * mu + EPSF);
  const float sb = s_b[blk];
  float Bv[NN];
#pragma unroll
  for (int n = 0; n < NN; n++)
    Bv[n] = Bp[blk * NN + n] + sb * tanhf(inv * (T1[n] - mu * T0[n]));

  short* Ho = Hst + (size_t)tok * NN * DD;
  if (LAST) {
    const float bsum = Bv[0] + Bv[1] + Bv[2] + Bv[3];
    float* orow = out + (size_t)tok * DD;
#pragma unroll
    for (int j = 0; j < 4; j++) {
      const int d0 = lane * 8 + j * 512;
      bf16x8 hrow[NN];
#pragma unroll
      for (int n = 0; n < NN; n++) hrow[n] = *(const bf16x8*)(Ho + n * DD + d0);
      f32x4 o0, o1;
#pragma unroll
      for (int q = 0; q < 8; q++) {
        const float hv = bf2f(h2r[j][q]);
        float s = hv * bsum;
#pragma unroll
        for (int n = 0; n < NN; n++) s += bf2f(hrow[n][q]);
        if (q < 4) o0[q] = s; else o1[q - 4] = s;
      }
      *(f32x4*)(orow + d0) = o0;
      *(f32x4*)(orow + d0 + 4) = o1;
    }
  } else {
#pragma unroll
    for (int j = 0; j < 4; j++) {
      const int d0 = lane * 8 + j * 512;
#pragma unroll
      for (int n = 0; n < NN; n++) {
        bf16x8 hrow = *(const bf16x8*)(Ho + n * DD + d0);
        bf16x8 o;
#pragma unroll
        for (int q = 0; q < 8; q++)
          o[q] = f2bf(bf2f(hrow[q]) + bf2f(h2r[j][q]) * Bv[n]);
        *(bf16x8*)(Ho + n * DD + d0) = o;
      }
    }
  }
}

extern "C" void kernel_launch(void* const* d_in, const int* in_sizes, int n_in,
                              void* d_out, int out_size, void* d_ws,
                              size_t ws_size, hipStream_t stream) {
  const float* x = (const float*)d_in[0];
  const float* A_m = (const float*)d_in[1];
  const float* A_r = (const float*)d_in[2];
  const float* Bp = (const float*)d_in[3];
  const float* W_m = (const float*)d_in[4];
  const float* W_r = (const float*)d_in[5];
  const float* W_b = (const float*)d_in[6];
  const float* s_a = (const float*)d_in[7];
  const float* s_b = (const float*)d_in[8];
  const float* dyn_gamma = (const float*)d_in[9];
  const float* norm_gamma = (const float*)d_in[10];
  const float* norm_beta = (const float*)d_in[11];
  const float* Wblk = (const float*)d_in[12];
  const float* bblk = (const float*)d_in[13];
  float* out = (float*)d_out;

  char* ws = (char*)d_ws;
  short* Hst = (short*)(ws);                      // 4096*4*2048*2 = 64 MiB
  short* hnorm = (short*)(ws + 67108864);         // 16 MiB
  short* h2 = (short*)(ws + 83886080);            // 16 MiB
  short* Wt = (short*)(ws + 100663296);           // 4*2048*2048*2 = 32 MiB

  dim3 tb(256);
  transpose_wblk<<<dim3(32, 32, 4), tb, 0, stream>>>(Wblk, Wt);
  for (int i = 0; i < LL; i++) {
    if (i == 0)
      width_kernel<true><<<1024, tb, 0, stream>>>(x, Hst, hnorm, A_m, A_r, W_m,
                                                  W_r, s_a, dyn_gamma,
                                                  norm_gamma, norm_beta, i);
    else
      width_kernel<false><<<1024, tb, 0, stream>>>(x, Hst, hnorm, A_m, A_r, W_m,
                                                   W_r, s_a, dyn_gamma,
                                                   norm_gamma, norm_beta, i);
    gemm_kernel<<<dim3(32, 16), tb, 0, stream>>>(
        hnorm, Wt + (size_t)i * DD * DD, bblk + i * DD, h2);
    if (i == LL - 1)
      depth_kernel<true><<<1024, tb, 0, stream>>>(h2, Hst, out, Bp, W_b, s_b,
                                                  dyn_gamma, i);
    else
      depth_kernel<false><<<1024, tb, 0, stream>>>(h2, Hst, out, Bp, W_b, s_b,
                                                   dyn_gamma, i);
  }
}

// Round 2
// 498.512 us; speedup vs baseline: 1.0216x; 1.0216x over previous
//
#include <hip/hip_runtime.h>
#include <hip/hip_bf16.h>

// HCNet: L=4 hyper-connection blocks, N=4, D=2048, B*T=4096 tokens.
// R1: (a) gemm gets XOR-swizzled LDS (both-sides involution) + double-buffered
//     prefetch-before-compute; (b) depth(i)+width(i+1) fused to keep H in regs.

#define DD 2048
#define NN 4
#define LL 4
#define NTOK 4096
#define EPSF 1e-5f

typedef __attribute__((ext_vector_type(8))) short bf16x8;
typedef __attribute__((ext_vector_type(4))) float f32x4;

__device__ __forceinline__ float bf2f(short u) {
  union { unsigned int i; float f; } v;
  v.i = ((unsigned int)(unsigned short)u) << 16;
  return v.f;
}
__device__ __forceinline__ short f2bf(float f) {
  union { float f; unsigned int i; } v; v.f = f;
  unsigned int x = v.i;
  return (short)((x + 0x7fffu + ((x >> 16) & 1u)) >> 16);  // RNE
}
__device__ __forceinline__ float wred(float v) {
#pragma unroll
  for (int off = 32; off > 0; off >>= 1) v += __shfl_xor(v, off, 64);
  return v;
}
__device__ __forceinline__ void ld16(const void* g, void* l) {
  __builtin_amdgcn_global_load_lds(
      (const __attribute__((address_space(1))) void*)g,
      (__attribute__((address_space(3))) void*)l, 16, 0, 0);
}

// ---------------- transpose Wblk[l][d][e] (f32) -> Wt[l][e][d] (bf16) -------
__global__ __launch_bounds__(256) void transpose_wblk(
    const float* __restrict__ W, short* __restrict__ Wt) {
  __shared__ float tile[64][65];
  const int blk = blockIdx.z;
  const int c0 = blockIdx.x * 64;
  const int r0 = blockIdx.y * 64;
  const float* Ws = W + (size_t)blk * DD * DD;
  short* Wd = Wt + (size_t)blk * DD * DD;
  const int tx = threadIdx.x & 63, ty = threadIdx.x >> 6;
#pragma unroll
  for (int r = 0; r < 16; r++) {
    const int row = ty + r * 4;
    tile[row][tx] = Ws[(size_t)(r0 + row) * DD + c0 + tx];
  }
  __syncthreads();
#pragma unroll
  for (int r = 0; r < 16; r++) {
    const int row = ty + r * 4;
    Wd[(size_t)(c0 + row) * DD + r0 + tx] = f2bf(tile[tx][row]);
  }
}

// ---------------- width connections for block 0 (reads x f32) ---------------
__global__ __launch_bounds__(256) void width0_kernel(
    const float* __restrict__ x, short* __restrict__ Hst,
    short* __restrict__ hnorm, const float* __restrict__ A_m,
    const float* __restrict__ A_r, const float* __restrict__ W_m,
    const float* __restrict__ W_r, const float* __restrict__ s_a,
    const float* __restrict__ dyn_gamma, const float* __restrict__ norm_gamma,
    const float* __restrict__ norm_beta) {
  const int wave = threadIdx.x >> 6;
  const int lane = threadIdx.x & 63;
  const int tok = blockIdx.x * 4 + wave;
  const int blk = 0;
  const float* dg = dyn_gamma + blk * DD;
  const float* wm = W_m + blk * DD;
  const float* wr = W_r + (size_t)blk * DD * NN;

  bf16x8 hreg[4];  // all N rows identical at block 0
  const float* xr = x + (size_t)tok * DD;
#pragma unroll
  for (int j = 0; j < 4; j++) {
    const int d0 = lane * 8 + j * 512;
    f32x4 a = *(const f32x4*)(xr + d0);
    f32x4 b = *(const f32x4*)(xr + d0 + 4);
    bf16x8 p;
#pragma unroll
    for (int q = 0; q < 4; q++) { p[q] = f2bf(a[q]); p[4 + q] = f2bf(b[q]); }
    hreg[j] = p;
  }

  float sH = 0, sH2 = 0;
  float S1[5] = {0, 0, 0, 0, 0}, S0[5] = {0, 0, 0, 0, 0};
#pragma unroll
  for (int j = 0; j < 4; j++) {
    const int d0 = lane * 8 + j * 512;
    f32x4 g0 = *(const f32x4*)(dg + d0), g1 = *(const f32x4*)(dg + d0 + 4);
    f32x4 m0 = *(const f32x4*)(wm + d0), m1 = *(const f32x4*)(wm + d0 + 4);
    f32x4 rr[8];
#pragma unroll
    for (int q = 0; q < 8; q++) rr[q] = *(const f32x4*)(wr + (size_t)(d0 + q) * NN);
#pragma unroll
    for (int q = 0; q < 8; q++) {
      const float g = (q < 4) ? g0[q] : g1[q - 4];
      const float wmv = (q < 4) ? m0[q] : m1[q - 4];
      float gw[5];
      gw[0] = g * wmv;
      gw[1] = g * rr[q][0]; gw[2] = g * rr[q][1];
      gw[3] = g * rr[q][2]; gw[4] = g * rr[q][3];
      const float hv = bf2f(hreg[j][q]);
      sH += hv; sH2 += hv * hv;
#pragma unroll
      for (int m = 0; m < 5; m++) { S0[m] += gw[m]; S1[m] += hv * gw[m]; }
    }
  }
  sH = wred(sH); sH2 = wred(sH2);
#pragma unroll
  for (int m = 0; m < 5; m++) { S0[m] = wred(S0[m]); S1[m] = wred(S1[m]); }

  const float sa = s_a[blk];
  const float mu0 = sH * (1.f / DD);
  const float inv0 = rsqrtf(sH2 * (1.f / DD) - mu0 * mu0 + EPSF);
  float Am[NN], Ar[NN];  // rows identical: Am[n], Ar[n][m] -> per n same stats
#pragma unroll
  for (int n = 0; n < NN; n++)
    Am[n] = A_m[blk * NN + n] + sa * tanhf(inv0 * (S1[0] - mu0 * S0[0]));
  float ArM[NN][NN];
#pragma unroll
  for (int n = 0; n < NN; n++)
#pragma unroll
    for (int m = 0; m < NN; m++)
      ArM[n][m] = A_r[blk * NN * NN + n * NN + m] +
                  sa * tanhf(inv0 * (S1[1 + m] - mu0 * S0[1 + m]));

  short* Ho = Hst + (size_t)tok * NN * DD;
  float hbuf[4][8];
  float sh = 0.f, sh2 = 0.f;
#pragma unroll
  for (int j = 0; j < 4; j++) {
    const int d0 = lane * 8 + j * 512;
    bf16x8 outp[NN];
#pragma unroll
    for (int q = 0; q < 8; q++) {
      const float hv = bf2f(hreg[j][q]);
      float a0 = 0.f, am[NN] = {0, 0, 0, 0};
#pragma unroll
      for (int n = 0; n < NN; n++) {
        a0 += hv * Am[n];
#pragma unroll
        for (int m = 0; m < NN; m++) am[m] += hv * ArM[n][m];
      }
      hbuf[j][q] = a0; sh += a0; sh2 += a0 * a0;
#pragma unroll
      for (int m = 0; m < NN; m++) outp[m][q] = f2bf(am[m]);
    }
#pragma unroll
    for (int m = 0; m < NN; m++) *(bf16x8*)(Ho + m * DD + d0) = outp[m];
  }
  sh = wred(sh); sh2 = wred(sh2);
  const float mu = sh * (1.f / DD);
  const float inv = rsqrtf(sh2 * (1.f / DD) - mu * mu + EPSF);
  const float* ng = norm_gamma + blk * DD;
  const float* nb = norm_beta + blk * DD;
  short* hn = hnorm + (size_t)tok * DD;
#pragma unroll
  for (int j = 0; j < 4; j++) {
    const int d0 = lane * 8 + j * 512;
    f32x4 g0 = *(const f32x4*)(ng + d0), g1 = *(const f32x4*)(ng + d0 + 4);
    f32x4 b0 = *(const f32x4*)(nb + d0), b1 = *(const f32x4*)(nb + d0 + 4);
    bf16x8 o;
#pragma unroll
    for (int q = 0; q < 8; q++) {
      const float g = (q < 4) ? g0[q] : g1[q - 4];
      const float b = (q < 4) ? b0[q] : b1[q - 4];
      o[q] = f2bf((hbuf[j][q] - mu) * inv * g + b);
    }
    *(bf16x8*)(hn + d0) = o;
  }
}

// ---------------- block GEMM: h2 = hnorm @ Wblk^T + bias --------------------
// Double-buffered LDS, XOR-swizzled (both-sides): data of col-byte g in row r
// lives at LDS byte r*128 + (g ^ ((r&7)<<4)).
__global__ __launch_bounds__(256) void gemm_kernel(
    const short* __restrict__ A, const short* __restrict__ Bt,
    const float* __restrict__ bias, short* __restrict__ C) {
  __shared__ short lA[2][128 * 64];
  __shared__ short lB[2][128 * 64];
  const int tid = threadIdx.x;
  const int lane = tid & 63;
  const int wave = tid >> 6;
  const int m0 = blockIdx.x * 128, n0 = blockIdx.y * 128;
  const int wm = wave >> 1, wn = wave & 1;

  f32x4 acc[4][4] = {};

#define STAGE(buf, kt)                                                        \
  {                                                                           \
    const int k0 = (kt) * 64;                                                 \
    _Pragma("unroll") for (int c = 0; c < 4; c++) {                           \
      const int idx = c * 256 + tid;                                          \
      const int row = idx >> 3;                                               \
      const int colsw = (((idx & 7) ^ (row & 7)) * 8);                        \
      ld16(A + (size_t)(m0 + row) * DD + k0 + colsw,                          \
           (char*)&lA[buf][0] + idx * 16);                                    \
      ld16(Bt + (size_t)(n0 + row) * DD + k0 + colsw,                         \
           (char*)&lB[buf][0] + idx * 16);                                    \
    }                                                                         \
  }

  STAGE(0, 0);
  __syncthreads();

  for (int kt = 0; kt < 32; ++kt) {
    const int cur = kt & 1;
    if (kt < 31) STAGE(cur ^ 1, kt + 1);
    const char* bufA = (const char*)&lA[cur][0];
    const char* bufB = (const char*)&lB[cur][0];
#pragma unroll
    for (int kk = 0; kk < 2; ++kk) {
      const int gsw = (kk * 64 + (lane >> 4) * 16) ^ ((lane & 7) << 4);
      bf16x8 af[4], bfr[4];
#pragma unroll
      for (int m = 0; m < 4; m++) {
        const int r = wm * 64 + m * 16 + (lane & 15);
        af[m] = *(const bf16x8*)(bufA + r * 128 + gsw);
      }
#pragma unroll
      for (int n = 0; n < 4; n++) {
        const int r = wn * 64 + n * 16 + (lane & 15);
        bfr[n] = *(const bf16x8*)(bufB + r * 128 + gsw);
      }
#pragma unroll
      for (int m = 0; m < 4; m++)
#pragma unroll
        for (int n = 0; n < 4; n++)
          acc[m][n] = __builtin_amdgcn_mfma_f32_16x16x32_bf16(
              af[m], bfr[n], acc[m][n], 0, 0, 0);
    }
    __syncthreads();
  }
#undef STAGE

#pragma unroll
  for (int n = 0; n < 4; n++) {
    const int col = n0 + wn * 64 + n * 16 + (lane & 15);
    const float bv = bias[col];
#pragma unroll
    for (int m = 0; m < 4; m++) {
      const int rbase = m0 + wm * 64 + m * 16 + ((lane >> 4) << 2);
#pragma unroll
      for (int j = 0; j < 4; j++)
        C[(size_t)(rbase + j) * DD + col] = f2bf(acc[m][n][j] + bv);
    }
  }
}

// ---------------- fused depth(blk) + width(blk+1) ---------------------------
__global__ __launch_bounds__(256) void fused_dw(
    const short* __restrict__ h2, short* __restrict__ Hst,
    short* __restrict__ hnorm, const float* __restrict__ Bp,
    const float* __restrict__ W_b, const float* __restrict__ s_b,
    const float* __restrict__ A_m, const float* __restrict__ A_r,
    const float* __restrict__ W_m, const float* __restrict__ W_r,
    const float* __restrict__ s_a, const float* __restrict__ dyn_gamma,
    const float* __restrict__ norm_gamma, const float* __restrict__ norm_beta,
    int blk) {
  const int wave = threadIdx.x >> 6;
  const int lane = threadIdx.x & 63;
  const int tok = blockIdx.x * 4 + wave;
  const int nblk = blk + 1;
  const short* hr = h2 + (size_t)tok * DD;
  short* Ho = Hst + (size_t)tok * NN * DD;

  // ---- issue all big loads early ----
  bf16x8 h2r[4], hold[NN][4];
#pragma unroll
  for (int j = 0; j < 4; j++) {
    const int d0 = lane * 8 + j * 512;
    h2r[j] = *(const bf16x8*)(hr + d0);
#pragma unroll
    for (int n = 0; n < NN; n++)
      hold[n][j] = *(const bf16x8*)(Ho + n * DD + d0);
  }

  // ---- depth stats on h2 (dyn LN gamma of block `blk`) ----
  const float* dgd = dyn_gamma + blk * DD;
  const float* wb = W_b + (size_t)blk * DD * NN;
  float s1 = 0.f, s2 = 0.f, T1[NN] = {0, 0, 0, 0}, T0[NN] = {0, 0, 0, 0};
#pragma unroll
  for (int j = 0; j < 4; j++) {
    const int d0 = lane * 8 + j * 512;
    f32x4 g0 = *(const f32x4*)(dgd + d0), g1 = *(const f32x4*)(dgd + d0 + 4);
    f32x4 rr[8];
#pragma unroll
    for (int q = 0; q < 8; q++) rr[q] = *(const f32x4*)(wb + (size_t)(d0 + q) * NN);
#pragma unroll
    for (int q = 0; q < 8; q++) {
      const float g = (q < 4) ? g0[q] : g1[q - 4];
      const float hv = bf2f(h2r[j][q]);
      s1 += hv; s2 += hv * hv;
#pragma unroll
      for (int n = 0; n < NN; n++) {
        const float gw = g * rr[q][n];
        T0[n] += gw; T1[n] += hv * gw;
      }
    }
  }
  s1 = wred(s1); s2 = wred(s2);
#pragma unroll
  for (int n = 0; n < NN; n++) { T0[n] = wred(T0[n]); T1[n] = wred(T1[n]); }
  {
    const float mu = s1 * (1.f / DD);
    const float inv = rsqrtf(s2 * (1.f / DD) - mu * mu + EPSF);
    const float sb = s_b[blk];
    float Bv[NN];
#pragma unroll
    for (int n = 0; n < NN; n++)
      Bv[n] = Bp[blk * NN + n] + sb * tanhf(inv * (T1[n] - mu * T0[n]));
    // ---- H' = H + h2 * Bv  (bf16, matches unfused rounding) ----
#pragma unroll
    for (int n = 0; n < NN; n++)
#pragma unroll
      for (int j = 0; j < 4; j++) {
        bf16x8 o;
#pragma unroll
        for (int q = 0; q < 8; q++)
          o[q] = f2bf(bf2f(hold[n][j][q]) + bf2f(h2r[j][q]) * Bv[n]);
        hold[n][j] = o;
      }
  }

  // ---- width connections of block nblk on H' (in hold) ----
  const float* dg = dyn_gamma + nblk * DD;
  const float* wm = W_m + nblk * DD;
  const float* wr = W_r + (size_t)nblk * DD * NN;

  float sH[NN] = {0, 0, 0, 0}, sH2[NN] = {0, 0, 0, 0};
  float S1[NN][5];
  float S0[5] = {0, 0, 0, 0, 0};
#pragma unroll
  for (int n = 0; n < NN; n++)
#pragma unroll
    for (int m = 0; m < 5; m++) S1[n][m] = 0.f;

#pragma unroll
  for (int j = 0; j < 4; j++) {
    const int d0 = lane * 8 + j * 512;
    f32x4 g0 = *(const f32x4*)(dg + d0), g1 = *(const f32x4*)(dg + d0 + 4);
    f32x4 m0 = *(const f32x4*)(wm + d0), m1 = *(const f32x4*)(wm + d0 + 4);
    f32x4 rr[8];
#pragma unroll
    for (int q = 0; q < 8; q++) rr[q] = *(const f32x4*)(wr + (size_t)(d0 + q) * NN);
#pragma unroll
    for (int q = 0; q < 8; q++) {
      const float g = (q < 4) ? g0[q] : g1[q - 4];
      const float wmv = (q < 4) ? m0[q] : m1[q - 4];
      float gw[5];
      gw[0] = g * wmv;
      gw[1] = g * rr[q][0]; gw[2] = g * rr[q][1];
      gw[3] = g * rr[q][2]; gw[4] = g * rr[q][3];
#pragma unroll
      for (int m = 0; m < 5; m++) S0[m] += gw[m];
#pragma unroll
      for (int n = 0; n < NN; n++) {
        const float hv = bf2f(hold[n][j][q]);
        sH[n] += hv; sH2[n] += hv * hv;
#pragma unroll
        for (int m = 0; m < 5; m++) S1[n][m] += hv * gw[m];
      }
    }
  }
#pragma unroll
  for (int n = 0; n < NN; n++) { sH[n] = wred(sH[n]); sH2[n] = wred(sH2[n]); }
#pragma unroll
  for (int m = 0; m < 5; m++) S0[m] = wred(S0[m]);
#pragma unroll
  for (int n = 0; n < NN; n++)
#pragma unroll
    for (int m = 0; m < 5; m++) S1[n][m] = wred(S1[n][m]);

  const float sa = s_a[nblk];
  float Am[NN], Ar[NN][NN];
#pragma unroll
  for (int n = 0; n < NN; n++) {
    const float mu = sH[n] * (1.f / DD);
    const float var = sH2[n] * (1.f / DD) - mu * mu;
    const float inv = rsqrtf(var + EPSF);
    Am[n] = A_m[nblk * NN + n] + sa * tanhf(inv * (S1[n][0] - mu * S0[0]));
#pragma unroll
    for (int m = 0; m < NN; m++)
      Ar[n][m] = A_r[nblk * NN * NN + n * NN + m] +
                 sa * tanhf(inv * (S1[n][1 + m] - mu * S0[1 + m]));
  }

  float hbuf[4][8];
  float sh = 0.f, sh2 = 0.f;
#pragma unroll
  for (int j = 0; j < 4; j++) {
    const int d0 = lane * 8 + j * 512;
    bf16x8 outp[NN];
#pragma unroll
    for (int q = 0; q < 8; q++) {
      float a0 = 0.f, am0 = 0.f, am1 = 0.f, am2 = 0.f, am3 = 0.f;
#pragma unroll
      for (int n = 0; n < NN; n++) {
        const float hv = bf2f(hold[n][j][q]);
        a0 += hv * Am[n];
        am0 += hv * Ar[n][0];
        am1 += hv * Ar[n][1];
        am2 += hv * Ar[n][2];
        am3 += hv * Ar[n][3];
      }
      hbuf[j][q] = a0; sh += a0; sh2 += a0 * a0;
      outp[0][q] = f2bf(am0); outp[1][q] = f2bf(am1);
      outp[2][q] = f2bf(am2); outp[3][q] = f2bf(am3);
    }
#pragma unroll
    for (int m = 0; m < NN; m++) *(bf16x8*)(Ho + m * DD + d0) = outp[m];
  }
  sh = wred(sh); sh2 = wred(sh2);
  const float mu = sh * (1.f / DD);
  const float inv = rsqrtf(sh2 * (1.f / DD) - mu * mu + EPSF);
  const float* ng = norm_gamma + nblk * DD;
  const float* nb = norm_beta + nblk * DD;
  short* hn = hnorm + (size_t)tok * DD;
#pragma unroll
  for (int j = 0; j < 4; j++) {
    const int d0 = lane * 8 + j * 512;
    f32x4 g0 = *(const f32x4*)(ng + d0), g1 = *(const f32x4*)(ng + d0 + 4);
    f32x4 b0 = *(const f32x4*)(nb + d0), b1 = *(const f32x4*)(nb + d0 + 4);
    bf16x8 o;
#pragma unroll
    for (int q = 0; q < 8; q++) {
      const float g = (q < 4) ? g0[q] : g1[q - 4];
      const float b = (q < 4) ? b0[q] : b1[q - 4];
      o[q] = f2bf((hbuf[j][q] - mu) * inv * g + b);
    }
    *(bf16x8*)(hn + d0) = o;
  }
}

// ---------------- final depth (block 3) + output sum ------------------------
__global__ __launch_bounds__(256) void depth_last(
    const short* __restrict__ h2, const short* __restrict__ Hst,
    float* __restrict__ out, const float* __restrict__ Bp,
    const float* __restrict__ W_b, const float* __restrict__ s_b,
    const float* __restrict__ dyn_gamma, int blk) {
  const int wave = threadIdx.x >> 6;
  const int lane = threadIdx.x & 63;
  const int tok = blockIdx.x * 4 + wave;
  const short* hr = h2 + (size_t)tok * DD;
  const float* dg = dyn_gamma + blk * DD;
  const float* wb = W_b + (size_t)blk * DD * NN;

  bf16x8 h2r[4];
  float s1 = 0.f, s2 = 0.f, T1[NN] = {0, 0, 0, 0}, T0[NN] = {0, 0, 0, 0};
#pragma unroll
  for (int j = 0; j < 4; j++) {
    const int d0 = lane * 8 + j * 512;
    h2r[j] = *(const bf16x8*)(hr + d0);
    f32x4 g0 = *(const f32x4*)(dg + d0), g1 = *(const f32x4*)(dg + d0 + 4);
    f32x4 rr[8];
#pragma unroll
    for (int q = 0; q < 8; q++) rr[q] = *(const f32x4*)(wb + (size_t)(d0 + q) * NN);
#pragma unroll
    for (int q = 0; q < 8; q++) {
      const float g = (q < 4) ? g0[q] : g1[q - 4];
      const float hv = bf2f(h2r[j][q]);
      s1 += hv; s2 += hv * hv;
#pragma unroll
      for (int n = 0; n < NN; n++) {
        const float gw = g * rr[q][n];
        T0[n] += gw; T1[n] += hv * gw;
      }
    }
  }
  s1 = wred(s1); s2 = wred(s2);
#pragma unroll
  for (int n = 0; n < NN; n++) { T0[n] = wred(T0[n]); T1[n] = wred(T1[n]); }
  const float mu = s1 * (1.f / DD);
  const float inv = rsqrtf(s2 * (1.f / DD) - mu * mu + EPSF);
  const float sb = s_b[blk];
  float bsum = 0.f;
#pragma unroll
  for (int n = 0; n < NN; n++)
    bsum += Bp[blk * NN + n] + sb * tanhf(inv * (T1[n] - mu * T0[n]));

  const short* Ho = Hst + (size_t)tok * NN * DD;
  float* orow = out + (size_t)tok * DD;
#pragma unroll
  for (int j = 0; j < 4; j++) {
    const int d0 = lane * 8 + j * 512;
    bf16x8 hrow[NN];
#pragma unroll
    for (int n = 0; n < NN; n++) hrow[n] = *(const bf16x8*)(Ho + n * DD + d0);
    f32x4 o0, o1;
#pragma unroll
    for (int q = 0; q < 8; q++) {
      const float hv = bf2f(h2r[j][q]);
      float s = hv * bsum;
#pragma unroll
      for (int n = 0; n < NN; n++) s += bf2f(hrow[n][q]);
      if (q < 4) o0[q] = s; else o1[q - 4] = s;
    }
    *(f32x4*)(orow + d0) = o0;
    *(f32x4*)(orow + d0 + 4) = o1;
  }
}

extern "C" void kernel_launch(void* const* d_in, const int* in_sizes, int n_in,
                              void* d_out, int out_size, void* d_ws,
                              size_t ws_size, hipStream_t stream) {
  const float* x = (const float*)d_in[0];
  const float* A_m = (const float*)d_in[1];
  const float* A_r = (const float*)d_in[2];
  const float* Bp = (const float*)d_in[3];
  const float* W_m = (const float*)d_in[4];
  const float* W_r = (const float*)d_in[5];
  const float* W_b = (const float*)d_in[6];
  const float* s_a = (const float*)d_in[7];
  const float* s_b = (const float*)d_in[8];
  const float* dyn_gamma = (const float*)d_in[9];
  const float* norm_gamma = (const float*)d_in[10];
  const float* norm_beta = (const float*)d_in[11];
  const float* Wblk = (const float*)d_in[12];
  const float* bblk = (const float*)d_in[13];
  float* out = (float*)d_out;

  char* ws = (char*)d_ws;
  short* Hst = (short*)(ws);               // 64 MiB
  short* hnorm = (short*)(ws + 67108864);  // 16 MiB
  short* h2 = (short*)(ws + 83886080);     // 16 MiB
  short* Wt = (short*)(ws + 100663296);    // 32 MiB

  dim3 tb(256);
  transpose_wblk<<<dim3(32, 32, 4), tb, 0, stream>>>(Wblk, Wt);
  width0_kernel<<<1024, tb, 0, stream>>>(x, Hst, hnorm, A_m, A_r, W_m, W_r,
                                         s_a, dyn_gamma, norm_gamma, norm_beta);
  for (int i = 0; i < LL; i++) {
    gemm_kernel<<<dim3(32, 16), tb, 0, stream>>>(
        hnorm, Wt + (size_t)i * DD * DD, bblk + i * DD, h2);
    if (i < LL - 1)
      fused_dw<<<1024, tb, 0, stream>>>(h2, Hst, hnorm, Bp, W_b, s_b, A_m, A_r,
                                        W_m, W_r, s_a, dyn_gamma, norm_gamma,
                                        norm_beta, i);
    else
      depth_last<<<1024, tb, 0, stream>>>(h2, Hst, out, Bp, W_b, s_b,
                                          dyn_gamma, i);
  }
}